// Round 2
// baseline (122.159 us; speedup 1.0000x reference)
//
#include <hip/hip_runtime.h>
#include <hip/hip_cooperative_groups.h>

namespace cg = cooperative_groups;

// Problem geometry (fixed by the reference):
//   embeddings: (8, 2048, 768) fp32
//   W: (1536,) fp32  -> W_left = W[:768], W_right = W[768:]
//   b: (1,) fp32
//   out[b,i,j] = dot(emb[b,i,:], W_left) + dot(emb[b,j,:], W_right) + b[0]
#define PB_H 768
#define PB_L 2048
#define PB_B 8
#define PB_ROWS (PB_B * PB_L)        // 16384
#define NBLK 1024                    // 4 blocks/CU on 256 CUs -> co-resident
#define NTHR 256
#define TOTAL_THREADS (NBLK * NTHR)  // 262144
#define OUT_F4 (PB_ROWS * (PB_L / 4))        // 8,388,608 float4
#define F4_PER_THREAD (OUT_F4 / TOTAL_THREADS)  // 32

__global__ void __launch_bounds__(NTHR, 4)
probe_fused_kernel(const float* __restrict__ emb,
                   const float* __restrict__ W,
                   const float* __restrict__ bptr,
                   float* __restrict__ left,
                   float* __restrict__ right,
                   float4* __restrict__ out) {
    // ---- Phase 1: dual dot products, 4 rows per wave ----
    const int wave = (blockIdx.x << 2) + (threadIdx.x >> 6);  // [0, 4096)
    const int lane = threadIdx.x & 63;

    const float4* wl = reinterpret_cast<const float4*>(W);
    const float4* wr = reinterpret_cast<const float4*>(W + PB_H);
    const float bias = bptr[0];

    // Hoist W fragments (L1-resident after first touch; 6 float4 regs)
    float4 lv0 = wl[lane], lv1 = wl[64 + lane], lv2 = wl[128 + lane];
    float4 rv0 = wr[lane], rv1 = wr[64 + lane], rv2 = wr[128 + lane];

#pragma unroll
    for (int r = 0; r < 4; ++r) {
        const int row = (wave << 2) + r;  // [0, 16384)
        const float4* e = reinterpret_cast<const float4*>(emb + (size_t)row * PB_H);
        float4 e0 = e[lane], e1 = e[64 + lane], e2 = e[128 + lane];

        float accl = e0.x * lv0.x + e0.y * lv0.y + e0.z * lv0.z + e0.w * lv0.w
                   + e1.x * lv1.x + e1.y * lv1.y + e1.z * lv1.z + e1.w * lv1.w
                   + e2.x * lv2.x + e2.y * lv2.y + e2.z * lv2.z + e2.w * lv2.w;
        float accr = e0.x * rv0.x + e0.y * rv0.y + e0.z * rv0.z + e0.w * rv0.w
                   + e1.x * rv1.x + e1.y * rv1.y + e1.z * rv1.z + e1.w * rv1.w
                   + e2.x * rv2.x + e2.y * rv2.y + e2.z * rv2.z + e2.w * rv2.w;

#pragma unroll
        for (int off = 32; off >= 1; off >>= 1) {
            accl += __shfl_xor(accl, off);
            accr += __shfl_xor(accr, off);
        }
        if (lane == 0) {
            left[row]  = accl + bias;   // fold bias into left
            right[row] = accr;
        }
    }

    // ---- Grid-wide barrier ----
    cg::this_grid().sync();

    // ---- Phase 2: broadcast add, grid-stride float4 stores ----
    const int tid = blockIdx.x * NTHR + threadIdx.x;
#pragma unroll
    for (int it = 0; it < F4_PER_THREAD; ++it) {
        const long long t = (long long)tid + (long long)it * TOTAL_THREADS;
        const int j4  = (int)(t & 511);       // 512 float4 per output row
        const int row = (int)(t >> 9);        // b*2048 + i
        const int b   = row >> 11;

        const float lvv = left[row];
        const float4 rvv =
            reinterpret_cast<const float4*>(right + ((size_t)b << 11))[j4];

        float4 o;
        o.x = lvv + rvv.x;
        o.y = lvv + rvv.y;
        o.z = lvv + rvv.z;
        o.w = lvv + rvv.w;
        out[t] = o;
    }
}

extern "C" void kernel_launch(void* const* d_in, const int* in_sizes, int n_in,
                              void* d_out, int out_size, void* d_ws, size_t ws_size,
                              hipStream_t stream) {
    const float* emb  = (const float*)d_in[0];
    const float* W    = (const float*)d_in[1];
    const float* bias = (const float*)d_in[2];
    float4* out = (float4*)d_out;

    float* left  = (float*)d_ws;            // 16384 floats
    float* right = left + PB_ROWS;          // 16384 floats (128 KiB total)

    void* args[] = {(void*)&emb, (void*)&W, (void*)&bias,
                    (void*)&left, (void*)&right, (void*)&out};
    hipLaunchCooperativeKernel((const void*)probe_fused_kernel,
                               dim3(NBLK), dim3(NTHR), args, 0, stream);
}

// Round 4
// 34.889 us; speedup vs baseline: 3.5014x; 3.5014x over previous
//
#include <hip/hip_runtime.h>

// Problem geometry (fixed by the reference):
//   embeddings: (8, 2048, 768) fp32
//   W: (1536,) fp32  -> W_left = W[:768], W_right = W[768:]
//   b: (1,) fp32
//   out[b,i,j] = dot(emb[b,i,:], W_left) + dot(emb[b,j,:], W_right) + b[0]
#define PB_H 768
#define PB_L 2048
#define PB_B 8
#define PB_ROWS (PB_B * PB_L)   // 16384

// Native clang vector type — accepted by __builtin_nontemporal_* (HIP's
// float4 is a struct wrapper and is rejected).
typedef float f4x __attribute__((ext_vector_type(4)));

// Kernel 1: per-row dual dot product.
// One wave (64 lanes) per row; 4 waves per 256-thread block.
// Lane k reads float4s at offsets {0,64,128}+k -> three 1 KiB wave loads.
__global__ void probe_dot_kernel(const float* __restrict__ emb,
                                 const float* __restrict__ W,
                                 const float* __restrict__ bptr,
                                 float* __restrict__ left,
                                 float* __restrict__ right) {
    const int wave = threadIdx.x >> 6;
    const int lane = threadIdx.x & 63;
    const int row  = (blockIdx.x << 2) + wave;          // [0, 16384)

    const f4x* e  = reinterpret_cast<const f4x*>(emb + (size_t)row * PB_H);
    const f4x* wl = reinterpret_cast<const f4x*>(W);
    const f4x* wr = reinterpret_cast<const f4x*>(W + PB_H);

    float accl = 0.f, accr = 0.f;
#pragma unroll
    for (int k = 0; k < 3; ++k) {
        const int idx = k * 64 + lane;                  // float4 index within row
        f4x ev = __builtin_nontemporal_load(&e[idx]);   // streamed once
        f4x lv = wl[idx];
        f4x rv = wr[idx];
        accl += ev.x * lv.x + ev.y * lv.y + ev.z * lv.z + ev.w * lv.w;
        accr += ev.x * rv.x + ev.y * rv.y + ev.z * rv.z + ev.w * rv.w;
    }

    // 64-lane butterfly reduction
#pragma unroll
    for (int off = 32; off >= 1; off >>= 1) {
        accl += __shfl_xor(accl, off);
        accr += __shfl_xor(accr, off);
    }

    if (lane == 0) {
        left[row]  = accl + bptr[0];   // fold bias into left
        right[row] = accr;
    }
}

// Kernel 2: broadcast add. One block per output row (b,i); 256 threads,
// 2 float4 each (2048 floats = 8 KiB per row). left[row] is blockIdx-
// uniform -> scalar load. right chunk reads are 1 KiB coalesced and
// L2-resident (64 KiB total). Output stores nontemporal (write-once).
__global__ void probe_bcast_kernel(const float* __restrict__ left,
                                   const float* __restrict__ right,
                                   f4x* __restrict__ out) {
    const int row = blockIdx.x;             // b*2048 + i
    const int b   = row >> 11;
    const float lv = left[row];             // uniform scalar load

    const f4x* rrow = reinterpret_cast<const f4x*>(right + ((size_t)b << 11));
    f4x* orow = out + ((size_t)row << 9);   // 512 float4 per row

#pragma unroll
    for (int k = 0; k < 2; ++k) {
        const int j4 = threadIdx.x + (k << 8);
        f4x rv = rrow[j4];
        f4x o = rv + lv;                    // vector + broadcast scalar
        __builtin_nontemporal_store(o, &orow[j4]);
    }
}

extern "C" void kernel_launch(void* const* d_in, const int* in_sizes, int n_in,
                              void* d_out, int out_size, void* d_ws, size_t ws_size,
                              hipStream_t stream) {
    const float* emb  = (const float*)d_in[0];
    const float* W    = (const float*)d_in[1];
    const float* bias = (const float*)d_in[2];
    f4x* out = (f4x*)d_out;

    float* left  = (float*)d_ws;            // 16384 floats
    float* right = left + PB_ROWS;          // 16384 floats (128 KiB total)

    // Kernel 1: 16384 rows / 4 waves per block = 4096 blocks
    probe_dot_kernel<<<4096, 256, 0, stream>>>(emb, W, bias, left, right);

    // Kernel 2: one block per output row
    probe_bcast_kernel<<<PB_ROWS, 256, 0, stream>>>(left, right, out);
}